// Round 4
// baseline (878.239 us; speedup 1.0000x reference)
//
#include <hip/hip_runtime.h>

#define NPTS 400000
#define NXv 352
#define NYv 400
#define CANVAS 281600  // 2 * 1 * 400 * 352
#define G1B 1536       // gemm1 blocks (voxel-aligned ~260-pt ranges, 3/CU x 2 rounds)
#define MAXR 288       // max rows per gemm1 block (260 + snap margin)
#define G2B 512        // gemm2 blocks (2 per CU resident)
#define SCANB 275      // scan blocks: 275 * 1024 == CANVAS

typedef unsigned int uint;
typedef unsigned short ushort;
typedef __attribute__((ext_vector_type(8))) short short8;   // 8 bf16 (4 VGPRs)
typedef __attribute__((ext_vector_type(4))) float floatx4;  // MFMA acc

// round-to-nearest-even float -> bf16 pack of two values into one uint (a=low, b=high)
__device__ inline uint packbf(float a, float b) {
    uint ua = __float_as_uint(a);
    ua = (ua + 0x7fffu + ((ua >> 16) & 1u)) >> 16;
    uint ub = __float_as_uint(b);
    ub = (ub + 0x7fffu + ((ub >> 16) & 1u)) & 0xffff0000u;
    return ua | ub;
}
__device__ inline ushort bf16bits(float a) {
    uint u = __float_as_uint(a);
    return (ushort)((u + 0x7fffu + ((u >> 16) & 1u)) >> 16);
}
__device__ inline float lo16(uint u) { return __uint_as_float(u << 16); }
__device__ inline float hi16(uint u) { return __uint_as_float(u & 0xffff0000u); }
__device__ inline float bfval(ushort u) { return __uint_as_float(((uint)u) << 16); }

// ---------------- K1: voxel id + per-point position + counts  (+ fused W1 prep) -
__global__ void k_bucket(const int4* __restrict__ coors, const float* __restrict__ W1,
                         int* __restrict__ idxbuf, int* __restrict__ pidx,
                         uint* __restrict__ ucnt, ushort* __restrict__ w1t) {
    int b = blockIdx.x;
    if (b < 1563) {
        int i = b * 256 + threadIdx.x;
        if (i >= NPTS) return;
        int4 c = coors[i];                       // [b, z, y, x], NZ == 1
        int idx = ((c.x + c.y) * NYv + c.z) * NXv + c.w;
        idxbuf[i] = idx;
        pidx[i] = (int)atomicAdd(&ucnt[idx], 1u);
    } else {
        int i = (b - 1563) * 256 + threadIdx.x;  // 0..16383: W1 (KxN) -> W1T bf16 (NxK)
        int n = i & 127, k = i >> 7;
        w1t[n * 128 + k] = bf16bits(W1[k * 128 + n]);
    }
}

// ---------------- exclusive scan of ucnt -> voff (2 kernels) --------------------
__global__ __launch_bounds__(1024) void k_scanA(const uint* __restrict__ ucnt,
                                                uint* __restrict__ voff,
                                                uint* __restrict__ bsum) {
    __shared__ uint sh[1024];
    int t = threadIdx.x;
    int v = blockIdx.x * 1024 + t;
    uint val = ucnt[v];
    sh[t] = val;
    for (int off = 1; off < 1024; off <<= 1) {
        __syncthreads();
        uint x = (t >= off) ? sh[t - off] : 0u;
        __syncthreads();
        sh[t] += x;
    }
    uint incl = sh[t];
    voff[v] = incl - val;           // exclusive within block
    if (t == 1023) bsum[blockIdx.x] = incl;
}

__global__ __launch_bounds__(1024) void k_scanC(const uint* __restrict__ bsum,
                                                uint* __restrict__ voff) {
    __shared__ uint sh[1024];
    __shared__ uint bs[1024];
    int t = threadIdx.x;
    uint val = (t < SCANB) ? bsum[t] : 0u;
    sh[t] = val; bs[t] = val;
    for (int off = 1; off < 1024; off <<= 1) {
        __syncthreads();
        uint x = (t >= off) ? sh[t - off] : 0u;
        __syncthreads();
        sh[t] += x;
    }
    __syncthreads();
    uint off_ = sh[blockIdx.x] - bs[blockIdx.x];  // exclusive block offset
    int v = blockIdx.x * 1024 + t;
    voff[v] += off_;
    if (blockIdx.x == SCANB - 1 && t == 1023) voff[CANVAS] = NPTS;
}

// ---------------- permutation + feature sort: featS[j] = feat[i] ----------------
__global__ void k_perm(const int* __restrict__ idxbuf, const int* __restrict__ pidx,
                       const uint* __restrict__ voff, const float4* __restrict__ feat,
                       int* __restrict__ vidx, float4* __restrict__ featS) {
    int i = blockIdx.x * 256 + threadIdx.x;
    if (i >= NPTS) return;
    int idx = idxbuf[i];
    uint j = voff[idx] + (uint)pidx[i];
    vidx[j] = idx;
    featS[j] = feat[i];
}

// ---------------- K2: voxel-aligned range: mean + feat(10)@W0 + stats + segmax --
// Per block: voxel-aligned point range. Phases (all outer loops unroll-disabled to
// keep VGPR < 168 -- round-3's 256-VGPR spill was the 168us regression):
//   1. sv load + quarter cuts (snapped to voxel boundaries, monotone)
//   2. per-voxel mean (segment-start threads walk, avg 1.42 rows)
//   3. per-point ft(10) @ W0 -> pre-BN bf16 (x0u global + LDS tile)
//   4. column scan: scanner (c,q) sweeps rows [cut[q],cut[q+1]) once, computing
//      sum + sumsq + running segmax (flush = coalesced 128B row of v0pre)
// v0pre is pre-BN max: BN0 monotone (g0>0) so BN(max x) == max BN(x) bit-exactly.
__global__ __launch_bounds__(256, 3) void k_gemm1(
        const float4* __restrict__ featS, const int* __restrict__ vidx,
        const uint* __restrict__ voff, const float* __restrict__ W0,
        uint* __restrict__ x0u, ushort* __restrict__ v0pre, float* __restrict__ stats) {
    __shared__ float w0s[640];
    __shared__ float4 vmn[MAXR];                    // per-row voxel mean
    __shared__ int sv[MAXR];                        // voxel id per row
    __shared__ __align__(8) ushort tile[MAXR * 68]; // pre-BN bf16, row pad 68
    __shared__ float red[512];                      // stats reduce
    __shared__ int cuts[5];                         // voxel-aligned row quarters
    for (int t = threadIdx.x; t < 640; t += 256) w0s[t] = W0[t];

    // contiguous point range [ps, pe) aligned to voxel boundaries
    int p0 = (int)((long long)blockIdx.x * NPTS / G1B);
    int p1 = (int)((long long)(blockIdx.x + 1) * NPTS / G1B);
    int ps, pe;
    { int v = vidx[p0]; ps = (voff[v] == (uint)p0) ? p0 : (int)voff[v + 1]; }
    if (p1 >= NPTS) pe = NPTS;
    else { int v = vidx[p1]; pe = (voff[v] == (uint)p1) ? p1 : (int)voff[v + 1]; }
    int n = pe - ps;
    if (n <= 0) return;                              // uniform (ps/pe uniform)

    #pragma clang loop unroll(disable)
    for (int r = threadIdx.x; r < n; r += 256) sv[r] = vidx[ps + r];
    __syncthreads();

    if (threadIdx.x == 0) { cuts[0] = 0; cuts[4] = n; }
    else if (threadIdx.x < 4) {                      // snap quarter starts forward
        int c0 = (int)(((long long)n * threadIdx.x) >> 2);
        while (c0 < n && sv[c0] == sv[c0 - 1]) ++c0; // c0 >= n/4 >= 1
        cuts[threadIdx.x] = c0;
    }

    // per-voxel mean: segment-start threads walk their segment (avg 1.42 rows)
    #pragma clang loop unroll(disable)
    for (int r = threadIdx.x; r < n; r += 256) {
        if (r > 0 && sv[r] == sv[r - 1]) continue;
        int v = sv[r];
        float4 acc = featS[ps + r];
        int e = r + 1;
        while (e < n && sv[e] == v) {
            float4 f = featS[ps + e];
            acc.x += f.x; acc.y += f.y; acc.z += f.z; acc.w += f.w;
            ++e;
        }
        float inv = 1.0f / (float)(e - r);
        float4 mn = make_float4(acc.x * inv, acc.y * inv, acc.z * inv, acc.w * inv);
        #pragma clang loop unroll(disable)
        for (int r2 = r; r2 < e; ++r2) vmn[r2] = mn;
    }
    __syncthreads();

    // per-point: ft(10) @ W0 -> 64 pre-BN bf16 (x0u + tile)
    #pragma clang loop unroll(disable)
    for (int r = threadIdx.x; r < n; r += 256) {
        float4 f = featS[ps + r];                   // L1-hot from mean pass
        float4 vm = vmn[r];
        int idx = sv[r];
        int xq = idx % NXv;
        int yq = (idx / NXv) % NYv;
        float ft[10];
        ft[0] = f.x; ft[1] = f.y; ft[2] = f.z; ft[3] = f.w;
        ft[4] = f.x - vm.x;
        ft[5] = f.y - vm.y;
        ft[6] = f.z - vm.z;
        ft[7] = f.x - ((float)xq * 0.2f + 0.1f);    // VX/2 + PCR0
        ft[8] = f.y - ((float)yq * 0.2f - 39.9f);   // VY/2 + PCR1
        ft[9] = f.z + 1.0f;                         // z=0 -> -(VZ/2 + PCR2) = +1
        uint* o = x0u + (size_t)(ps + r) * 32;
        ushort* trow = &tile[r * 68];
        #pragma unroll
        for (int g = 0; g < 8; ++g) {
            float a[8];
            #pragma unroll
            for (int q = 0; q < 8; ++q) a[q] = 0.f;
            #pragma unroll
            for (int k = 0; k < 10; ++k) {
                float fk = ft[k];
                #pragma unroll
                for (int q = 0; q < 8; ++q) a[q] = fmaf(fk, w0s[k * 64 + g * 8 + q], a[q]);
            }
            uint4 w;
            w.x = packbf(a[0], a[1]); w.y = packbf(a[2], a[3]);
            w.z = packbf(a[4], a[5]); w.w = packbf(a[6], a[7]);
            *(uint4*)(o + g * 4) = w;
            ((uint2*)trow)[g * 2 + 0] = make_uint2(w.x, w.y);
            ((uint2*)trow)[g * 2 + 1] = make_uint2(w.z, w.w);
        }
    }
    __syncthreads();

    // column scan: stats + pre-BN segmax in one sweep (flushes wave-uniform,
    // 64 cols of a q-group write one coalesced 128B v0pre row per voxel)
    {
        int c = threadIdx.x & 63, q = threadIdx.x >> 6;
        int rlo = cuts[q], rhi = cuts[q + 1];
        float s = 0.f, sq = 0.f, run = -3.0e38f;
        int vcur = -1;
        #pragma clang loop unroll(disable)
        for (int r = rlo; r < rhi; ++r) {
            float x = bfval(tile[r * 68 + c]);
            int v = sv[r];                           // LDS broadcast
            if (v != vcur) {
                if (vcur >= 0) v0pre[(size_t)vcur * 64 + c] = bf16bits(run);
                vcur = v; run = x;
            } else {
                run = fmaxf(run, x);
            }
            s += x;
            sq = fmaf(x, x, sq);
        }
        if (vcur >= 0) v0pre[(size_t)vcur * 64 + c] = bf16bits(run);
        red[threadIdx.x] = s;
        red[256 + threadIdx.x] = sq;
    }
    __syncthreads();
    if (threadIdx.x < 64) {
        int c = threadIdx.x;
        float s = red[c] + red[64 + c] + red[128 + c] + red[192 + c];
        float sq = red[256 + c] + red[320 + c] + red[384 + c] + red[448 + c];
        atomicAdd(&stats[c], s);
        atomicAdd(&stats[64 + c], sq);
    }
}

// ---------------- GEMM2: voxel-aligned ranges, fused seg-max + stats ------------
// Role-split per strip: all waves MFMA -> CsT (column-major, conflict-free scan);
// then waves 0-1 stage next strip (BN0+ReLU on x0 and on gathered v0pre), waves
// 2-3 scan CsT columns (u32 = 2 rows/load, bank = c*37+r/2, gcd(37,32)=1: free).
__global__ __launch_bounds__(256) void k_gemm2p(
        const uint* __restrict__ x0u, const ushort* __restrict__ v0pre,
        const int* __restrict__ vidx, const uint* __restrict__ voff,
        const float* __restrict__ stats, const float* __restrict__ g0,
        const float* __restrict__ b0, const ushort* __restrict__ w1t,
        ushort* __restrict__ vmaxc, float* __restrict__ sums) {
    __shared__ __align__(16) ushort As[64 * 136];   // A tile (row pad +8)
    __shared__ __align__(8) ushort CsT[128 * 74];   // C tile, column-major pad 74
    __shared__ float s[128];                        // BN0 scale|shift
    __shared__ int svid[2][64];                     // voxel id per row (dbuf)

    int lane = threadIdx.x & 63, wid = threadIdx.x >> 6;
    int m = lane & 15, q = lane >> 4;   // C: col=ct*16+m, row=q*4+reg

    if (threadIdx.x < 64) {                          // BN0 finalize (folded bnfin)
        int c = threadIdx.x;
        float mu = stats[c] * (1.0f / NPTS);
        float var = stats[64 + c] * (1.0f / NPTS) - mu * mu;
        float sc = (1.0f / sqrtf(var + 1e-3f)) * g0[c];
        s[c] = sc;
        s[64 + c] = fmaf(-mu, sc, b0[c]);
    }

    // B fragments: W1T rows ct*16+m, k-chunks ks*32 + q*8 (L1/L2-hot, 32 KB)
    short8 breg[8][4];
    #pragma unroll
    for (int ct = 0; ct < 8; ++ct) {
        const ushort* br = &w1t[(ct * 16 + m) * 128 + q * 8];
        #pragma unroll
        for (int ks = 0; ks < 4; ++ks)
            breg[ct][ks] = *(const short8*)&br[ks * 32];
    }

    // contiguous point range [ps, pe) aligned to voxel boundaries
    int p0 = (int)((long long)blockIdx.x * NPTS / G2B);
    int p1 = (int)((long long)(blockIdx.x + 1) * NPTS / G2B);
    int ps, pe;
    { int v = vidx[p0]; ps = (voff[v] == (uint)p0) ? p0 : (int)voff[v + 1]; }
    if (p1 >= NPTS) pe = NPTS;
    else { int v = vidx[p1]; pe = (voff[v] == (uint)p1) ? p1 : (int)voff[v + 1]; }

    float run = -3.0e38f, csum = 0.f, csq = 0.f;
    int vcur = -1;

    // staging by 128 threads (waves 0-1); both halves apply BN0+ReLU
    auto stage = [&](int r0s, int p) {
        int nrows = min(64, pe - r0s);
        for (int i = threadIdx.x; i < 512; i += 128) {   // left: bnrelu0(x0)
            int r = i >> 3, ch = i & 7, cb = ch * 8;
            uint4 o4 = make_uint4(0u, 0u, 0u, 0u);
            if (r < nrows) {
                uint4 u = *(const uint4*)(x0u + (size_t)(r0s + r) * 32 + ch * 4);
                uint w[4] = {u.x, u.y, u.z, u.w}, o[4];
                #pragma unroll
                for (int q2 = 0; q2 < 4; ++q2) {
                    float a = fmaxf(fmaf(lo16(w[q2]), s[cb + 2 * q2], s[64 + cb + 2 * q2]), 0.f);
                    float b = fmaxf(fmaf(hi16(w[q2]), s[cb + 2 * q2 + 1], s[64 + cb + 2 * q2 + 1]), 0.f);
                    o[q2] = packbf(a, b);
                }
                o4 = make_uint4(o[0], o[1], o[2], o[3]);
            }
            *(uint4*)&As[r * 136 + ch * 8] = o4;
        }
        for (int i = threadIdx.x; i < 512; i += 128) {   // right: bnrelu0(v0pre)
            int r = i >> 3, ch = i & 7, cb = ch * 8;
            uint4 o4 = make_uint4(0u, 0u, 0u, 0u);
            if (r < nrows) {
                const uint* vp = (const uint*)(v0pre + (size_t)vidx[r0s + r] * 64);
                uint4 u = *(const uint4*)(vp + ch * 4);
                uint w[4] = {u.x, u.y, u.z, u.w}, o[4];
                #pragma unroll
                for (int q2 = 0; q2 < 4; ++q2) {
                    float a = fmaxf(fmaf(lo16(w[q2]), s[cb + 2 * q2], s[64 + cb + 2 * q2]), 0.f);
                    float b = fmaxf(fmaf(hi16(w[q2]), s[cb + 2 * q2 + 1], s[64 + cb + 2 * q2 + 1]), 0.f);
                    o[q2] = packbf(a, b);
                }
                o4 = make_uint4(o[0], o[1], o[2], o[3]);
            }
            *(uint4*)&As[r * 136 + 64 + ch * 8] = o4;
        }
        if (threadIdx.x < 64)
            svid[p][threadIdx.x] = (threadIdx.x < nrows) ? vidx[r0s + threadIdx.x] : -1;
    };

    __syncthreads();  // s ready
    if (threadIdx.x < 128 && ps < pe) stage(ps, 0);
    __syncthreads();  // As/svid[0] ready

    int sp = 0;
    for (int r0 = ps; r0 < pe; r0 += 64, sp ^= 1) {
        // MFMA phase: all waves
        const ushort* ar = &As[(wid * 16 + m) * 136 + q * 8];
        short8 a0 = *(const short8*)&ar[0];
        short8 a1 = *(const short8*)&ar[32];
        short8 a2 = *(const short8*)&ar[64];
        short8 a3 = *(const short8*)&ar[96];
        #pragma unroll
        for (int ct = 0; ct < 8; ++ct) {
            floatx4 acc = {0.f, 0.f, 0.f, 0.f};
            acc = __builtin_amdgcn_mfma_f32_16x16x32_bf16(a0, breg[ct][0], acc, 0, 0, 0);
            acc = __builtin_amdgcn_mfma_f32_16x16x32_bf16(a1, breg[ct][1], acc, 0, 0, 0);
            acc = __builtin_amdgcn_mfma_f32_16x16x32_bf16(a2, breg[ct][2], acc, 0, 0, 0);
            acc = __builtin_amdgcn_mfma_f32_16x16x32_bf16(a3, breg[ct][3], acc, 0, 0, 0);
            // column-major store: rows q*4..q*4+3 of column ct*16+m (2x b32)
            uint* cp = (uint*)&CsT[(ct * 16 + m) * 74 + wid * 16 + q * 4];
            cp[0] = packbf(acc[0], acc[1]);
            cp[1] = packbf(acc[2], acc[3]);
        }
        __syncthreads();  // CsT ready; As frag reads done

        if (threadIdx.x < 128) {
            if (r0 + 64 < pe) stage(r0 + 64, sp ^ 1);   // overwrite As for next strip
        } else {
            int c = threadIdx.x - 128;                   // segmented max over CsT col c
            const uint* crow = (const uint*)&CsT[c * 74];
            #pragma unroll 4
            for (int rp = 0; rp < 32; ++rp) {
                uint u = crow[rp];                       // rows 2rp, 2rp+1
                int va = svid[sp][2 * rp], vb = svid[sp][2 * rp + 1];
                float xa = lo16(u), xb = hi16(u);
                bool brk = (va != vcur);
                if (brk && vcur >= 0) vmaxc[(size_t)vcur * 128 + c] = bf16bits(run);
                run = brk ? xa : fmaxf(run, xa);
                vcur = va;
                csum += xa; csq = fmaf(xa, xa, csq);
                brk = (vb != vcur);
                if (brk && vcur >= 0) vmaxc[(size_t)vcur * 128 + c] = bf16bits(run);
                run = brk ? xb : fmaxf(run, xb);
                vcur = vb;
                csum += xb; csq = fmaf(xb, xb, csq);
            }
        }
        __syncthreads();  // next As/svid ready; CsT free
    }

    if (threadIdx.x >= 128) {
        int c = threadIdx.x - 128;
        if (vcur >= 0) vmaxc[(size_t)vcur * 128 + c] = bf16bits(run);
        atomicAdd(&sums[c], csum);
        atomicAdd(&sums[128 + c], csq);
    }
}

// ---------------- BN1 finalize + ReLU over voxel maxes -> dense fp32 output -----
__global__ __launch_bounds__(256) void k_bnout(const ushort* __restrict__ vmaxc,
        const uint* __restrict__ voff, const float* __restrict__ stats,
        const float* __restrict__ g1, const float* __restrict__ b1,
        float4* __restrict__ out) {
    __shared__ float s[256];
    if (threadIdx.x < 128) {
        int c = threadIdx.x;
        float mu = stats[128 + c] * (1.0f / NPTS);
        float var = stats[256 + c] * (1.0f / NPTS) - mu * mu;
        float sc = (1.0f / sqrtf(var + 1e-3f)) * g1[c];
        s[c] = sc;
        s[128 + c] = fmaf(-mu, sc, b1[c]);
    }
    __syncthreads();
    int t = blockIdx.x * 256 + threadIdx.x;
    int v = t >> 5;
    if (v >= CANVAS) return;
    int c = (t & 31) << 2;
    float4 m = make_float4(0.f, 0.f, 0.f, 0.f);
    if (voff[v + 1] != voff[v]) {      // nonempty: read max, apply monotone BN+ReLU
        uint2 u = *(const uint2*)(vmaxc + (size_t)v * 128 + c);
        m.x = fmaxf(fmaf(lo16(u.x), s[c + 0], s[128 + c + 0]), 0.f);
        m.y = fmaxf(fmaf(hi16(u.x), s[c + 1], s[128 + c + 1]), 0.f);
        m.z = fmaxf(fmaf(lo16(u.y), s[c + 2], s[128 + c + 2]), 0.f);
        m.w = fmaxf(fmaf(hi16(u.y), s[c + 3], s[128 + c + 3]), 0.f);
    }
    out[(size_t)v * 32 + (c >> 2)] = m;
}

extern "C" void kernel_launch(void* const* d_in, const int* in_sizes, int n_in,
                              void* d_out, int out_size, void* d_ws, size_t ws_size,
                              hipStream_t stream) {
    const float4* feat  = (const float4*)d_in[0];
    const int4*   coors = (const int4*)d_in[1];
    const float*  W0    = (const float*)d_in[2];
    const float*  g0    = (const float*)d_in[3];
    const float*  b0    = (const float*)d_in[4];
    const float*  W1    = (const float*)d_in[5];
    const float*  g1    = (const float*)d_in[6];
    const float*  b1    = (const float*)d_in[7];

    char* ws = (char*)d_ws;
    // workspace layout (bytes)
    int*    idxbuf = (int*)(ws + 0);               //   1,600,000
    int*    pidx   = (int*)(ws + 1600000);         //   1,600,000
    uint*   ucnt   = (uint*)(ws + 3200000);        //   1,126,400 ┐ one memset
    float*  stats  = (float*)(ws + 4326400);       //       3,072 ┘ (768 floats)
    //   [0:64] sum0, [64:128] sq0, [128:256] sum1, [256:384] sq1
    uint*   voff   = (uint*)(ws + 4329472);        //   1,126,416 (CANVAS+1)
    uint*   bsum   = (uint*)(ws + 5455888);        //       4,096
    int*    vidx   = (int*)(ws + 5459984);         //   1,600,000
    float*  featS  = (float*)(ws + 7059984);       //   6,400,000 (sorted float4)
    ushort* w1t    = (ushort*)(ws + 17965584);     //      32,768
    uint*   x0u    = (uint*)(ws + 17998352);       //  51,200,000 (pre-BN bf16, sorted)
    ushort* v0pre  = (ushort*)(ws + 69198352);     //  36,044,800 (pre-BN0 voxel max, bf16)
    ushort* vmaxc  = (ushort*)(ws + 105243152);    //  72,089,600 (pre-BN1 voxel max, bf16)
    // total: 177,332,752 bytes

    hipMemsetAsync(ws + 3200000, 0, 1129472, stream);  // ucnt + stats in one shot

    const int BLK = 256;
    int gpts = (NPTS + BLK - 1) / BLK;    // 1563

    k_bucket<<<gpts + 64, BLK, 0, stream>>>(coors, W1, idxbuf, pidx, ucnt, w1t);
    k_scanA<<<SCANB, 1024, 0, stream>>>(ucnt, voff, bsum);
    k_scanC<<<SCANB, 1024, 0, stream>>>(bsum, voff);
    k_perm<<<gpts, BLK, 0, stream>>>(idxbuf, pidx, voff, feat, vidx, (float4*)featS);
    k_gemm1<<<G1B, BLK, 0, stream>>>((const float4*)featS, vidx, voff, W0,
                                     x0u, v0pre, stats);
    k_gemm2p<<<G2B, BLK, 0, stream>>>(x0u, v0pre, vidx, voff, stats, g0, b0, w1t,
                                      vmaxc, stats + 128);
    k_bnout<<<CANVAS * 32 / BLK, BLK, 0, stream>>>(vmaxc, voff, stats, g1, b1,
                                                   (float4*)d_out);
}

// Round 5
// 441.920 us; speedup vs baseline: 1.9873x; 1.9873x over previous
//
#include <hip/hip_runtime.h>

#define NPTS 400000
#define NXv 352
#define NYv 400
#define CANVAS 281600  // 2 * 1 * 400 * 352
#define G2B 512        // gemm2 blocks (2 per CU resident)
#define SCANB 275      // scan blocks: 275 * 1024 == CANVAS

typedef unsigned int uint;
typedef unsigned short ushort;
typedef __attribute__((ext_vector_type(8))) short short8;   // 8 bf16 (4 VGPRs)
typedef __attribute__((ext_vector_type(4))) float floatx4;  // MFMA acc

// round-to-nearest-even float -> bf16 pack of two values into one uint (a=low, b=high)
__device__ inline uint packbf(float a, float b) {
    uint ua = __float_as_uint(a);
    ua = (ua + 0x7fffu + ((ua >> 16) & 1u)) >> 16;
    uint ub = __float_as_uint(b);
    ub = (ub + 0x7fffu + ((ub >> 16) & 1u)) & 0xffff0000u;
    return ua | ub;
}
__device__ inline ushort bf16bits(float a) {
    uint u = __float_as_uint(a);
    return (ushort)((u + 0x7fffu + ((u >> 16) & 1u)) >> 16);
}
__device__ inline float lo16(uint u) { return __uint_as_float(u << 16); }
__device__ inline float hi16(uint u) { return __uint_as_float(u & 0xffff0000u); }
__device__ inline float bfval(ushort u) { return __uint_as_float(((uint)u) << 16); }

// ---------------- K1: voxel id + per-point position + counts  (+ fused W1 prep) -
__global__ void k_bucket(const int4* __restrict__ coors, const float* __restrict__ W1,
                         int* __restrict__ idxbuf, int* __restrict__ pidx,
                         uint* __restrict__ ucnt, ushort* __restrict__ w1t) {
    int b = blockIdx.x;
    if (b < 1563) {
        int i = b * 256 + threadIdx.x;
        if (i >= NPTS) return;
        int4 c = coors[i];                       // [b, z, y, x], NZ == 1
        int idx = ((c.x + c.y) * NYv + c.z) * NXv + c.w;
        idxbuf[i] = idx;
        pidx[i] = (int)atomicAdd(&ucnt[idx], 1u);
    } else {
        int i = (b - 1563) * 256 + threadIdx.x;  // 0..16383: W1 (KxN) -> W1T bf16 (NxK)
        int n = i & 127, k = i >> 7;
        w1t[n * 128 + k] = bf16bits(W1[k * 128 + n]);
    }
}

// ---------------- exclusive scan of ucnt -> voff (2 kernels) --------------------
__global__ __launch_bounds__(1024) void k_scanA(const uint* __restrict__ ucnt,
                                                uint* __restrict__ voff,
                                                uint* __restrict__ bsum) {
    __shared__ uint sh[1024];
    int t = threadIdx.x;
    int v = blockIdx.x * 1024 + t;
    uint val = ucnt[v];
    sh[t] = val;
    for (int off = 1; off < 1024; off <<= 1) {
        __syncthreads();
        uint x = (t >= off) ? sh[t - off] : 0u;
        __syncthreads();
        sh[t] += x;
    }
    uint incl = sh[t];
    voff[v] = incl - val;           // exclusive within block
    if (t == 1023) bsum[blockIdx.x] = incl;
}

__global__ __launch_bounds__(1024) void k_scanC(const uint* __restrict__ bsum,
                                                uint* __restrict__ voff) {
    __shared__ uint sh[1024];
    __shared__ uint bs[1024];
    int t = threadIdx.x;
    uint val = (t < SCANB) ? bsum[t] : 0u;
    sh[t] = val; bs[t] = val;
    for (int off = 1; off < 1024; off <<= 1) {
        __syncthreads();
        uint x = (t >= off) ? sh[t - off] : 0u;
        __syncthreads();
        sh[t] += x;
    }
    __syncthreads();
    uint off_ = sh[blockIdx.x] - bs[blockIdx.x];  // exclusive block offset
    int v = blockIdx.x * 1024 + t;
    voff[v] += off_;
    if (blockIdx.x == SCANB - 1 && t == 1023) voff[CANVAS] = NPTS;
}

// ---------------- permutation + feature sort: featS[j] = feat[i] ----------------
__global__ void k_perm(const int* __restrict__ idxbuf, const int* __restrict__ pidx,
                       const uint* __restrict__ voff, const float4* __restrict__ feat,
                       int* __restrict__ vidx, float4* __restrict__ featS) {
    int i = blockIdx.x * 256 + threadIdx.x;
    if (i >= NPTS) return;
    int idx = idxbuf[i];
    uint j = voff[idx] + (uint)pidx[i];
    vidx[j] = idx;
    featS[j] = feat[i];
}

// ---------------- per-voxel mean via sequential segment scan --------------------
__global__ void k_vmean(const float4* __restrict__ featS, const uint* __restrict__ voff,
                        float4* __restrict__ vmean) {
    int v = blockIdx.x * 256 + threadIdx.x;
    if (v >= CANVAS) return;
    uint s_ = voff[v], e_ = voff[v + 1];
    float4 s = make_float4(0.f, 0.f, 0.f, 0.f);
    for (uint j = s_; j < e_; ++j) {
        float4 f = featS[j];
        s.x += f.x; s.y += f.y; s.z += f.z; s.w += f.w;
    }
    float inv = 1.0f / (float)max((int)(e_ - s_), 1);
    vmean[v] = make_float4(s.x * inv, s.y * inv, s.z * inv, s.w * inv);
}

// ---------------- K2: feat(10) build + GEMM1 + fused column stats ---------------
__global__ __launch_bounds__(256) void k_gemm1(
        const float4* __restrict__ featS, const int* __restrict__ vidx,
        const float4* __restrict__ vmean, const float* __restrict__ W0,
        uint* __restrict__ x0u, float* __restrict__ stats) {
    __shared__ float w0s[640];
    __shared__ __align__(8) ushort tile[256 * 68];  // row pad 68 breaks bank alias
    __shared__ float ps[128], qs[128];
    for (int t = threadIdx.x; t < 640; t += 256) w0s[t] = W0[t];
    __syncthreads();
    int j = blockIdx.x * 256 + threadIdx.x;
    bool valid = j < NPTS;
    ushort* trow = &tile[threadIdx.x * 68];
    if (valid) {
        float4 f = featS[j];
        int idx = vidx[j];
        float4 vm = vmean[idx];
        int xq = idx % NXv;            // voxel x
        int yq = (idx / NXv) % NYv;    // voxel y  (z == 0 always)
        float ft[10];
        ft[0] = f.x; ft[1] = f.y; ft[2] = f.z; ft[3] = f.w;
        ft[4] = f.x - vm.x;
        ft[5] = f.y - vm.y;
        ft[6] = f.z - vm.z;
        ft[7] = f.x - ((float)xq * 0.2f + 0.1f);    // VX/2 + PCR0
        ft[8] = f.y - ((float)yq * 0.2f - 39.9f);   // VY/2 + PCR1
        ft[9] = f.z + 1.0f;                         // z=0 -> -(VZ/2 + PCR2) = +1
        uint* o = x0u + (size_t)j * 32;
        #pragma unroll
        for (int g = 0; g < 8; ++g) {
            float a[8];
            #pragma unroll
            for (int q = 0; q < 8; ++q) a[q] = 0.f;
            #pragma unroll
            for (int k = 0; k < 10; ++k) {
                float fk = ft[k];
                #pragma unroll
                for (int q = 0; q < 8; ++q) a[q] = fmaf(fk, w0s[k * 64 + g * 8 + q], a[q]);
            }
            uint4 w;
            w.x = packbf(a[0], a[1]); w.y = packbf(a[2], a[3]);
            w.z = packbf(a[4], a[5]); w.w = packbf(a[6], a[7]);
            *(uint4*)(o + g * 4) = w;
            ((uint2*)trow)[g * 2 + 0] = make_uint2(w.x, w.y);
            ((uint2*)trow)[g * 2 + 1] = make_uint2(w.z, w.w);
        }
    } else {
        #pragma unroll
        for (int g = 0; g < 16; ++g) ((uint2*)trow)[g] = make_uint2(0u, 0u);
    }
    __syncthreads();
    if (threadIdx.x < 128) {
        int c = threadIdx.x & 63, half = threadIdx.x >> 6;
        float s = 0.f, q = 0.f;
        for (int r = half * 128; r < half * 128 + 128; ++r) {
            float xv = bfval(tile[r * 68 + c]);
            s += xv;
            q = fmaf(xv, xv, q);
        }
        ps[half * 64 + c] = s;
        qs[half * 64 + c] = q;
    }
    __syncthreads();
    if (threadIdx.x < 64) {
        int c = threadIdx.x;
        atomicAdd(&stats[c], ps[c] + ps[64 + c]);
        atomicAdd(&stats[64 + c], qs[c] + qs[64 + c]);
    }
}

// ---------------- segment-max over sorted x0, BN0+ReLU, bf16 out ----------------
// BN0 finalize folded in (per-block, from raw sums); empty voxels skipped.
__global__ void k_vmax0(const uint* __restrict__ x0u, const uint* __restrict__ voff,
                        const float* __restrict__ stats, const float* __restrict__ g0,
                        const float* __restrict__ b0, uint* __restrict__ v0u) {
    __shared__ float s[128];
    if (threadIdx.x < 64) {
        int c = threadIdx.x;
        float mu = stats[c] * (1.0f / NPTS);
        float var = stats[64 + c] * (1.0f / NPTS) - mu * mu;
        float sc = (1.0f / sqrtf(var + 1e-3f)) * g0[c];
        s[c] = sc;
        s[64 + c] = fmaf(-mu, sc, b0[c]);
    }
    __syncthreads();
    int t = blockIdx.x * 256 + threadIdx.x;
    int v = t >> 4;
    if (v >= CANVAS) return;
    uint s_ = voff[v], e_ = voff[v + 1];
    if (s_ == e_) return;              // empty voxel: never read downstream
    int c = (t & 15) << 2;
    float4 m = make_float4(0.f, 0.f, 0.f, 0.f);
    for (uint j = s_; j < e_; ++j) {
        uint2 u = *(const uint2*)(x0u + (size_t)j * 32 + (c >> 1));
        m.x = fmaxf(m.x, fmaf(lo16(u.x), s[c + 0], s[64 + c + 0]));
        m.y = fmaxf(m.y, fmaf(hi16(u.x), s[c + 1], s[64 + c + 1]));
        m.z = fmaxf(m.z, fmaf(lo16(u.y), s[c + 2], s[64 + c + 2]));
        m.w = fmaxf(m.w, fmaf(hi16(u.y), s[c + 3], s[64 + c + 3]));
    }
    uint2 o; o.x = packbf(m.x, m.y); o.y = packbf(m.z, m.w);
    *(uint2*)(v0u + (size_t)v * 32 + (c >> 1)) = o;
}

// ---------------- GEMM2: voxel-aligned ranges, fused seg-max + stats ------------
// Role-split per strip: all waves MFMA -> CsT (column-major: scan is conflict-free,
// bank = c*37+rp mod 32, gcd(37,32)=1); then waves 0-1 stage next strip (BN0+ReLU
// on x0, v0u gather), waves 2-3 scan CsT columns (u32 = 2 rows/load).
// B (w1t, 32 KB, L2-hot) pinned in 32 short8 VGPRs per thread (round-2 win).
__global__ __launch_bounds__(256) void k_gemm2p(
        const uint* __restrict__ x0u, const uint* __restrict__ v0u,
        const int* __restrict__ vidx, const uint* __restrict__ voff,
        const float* __restrict__ stats, const float* __restrict__ g0,
        const float* __restrict__ b0, const ushort* __restrict__ w1t,
        ushort* __restrict__ vmaxc, float* __restrict__ sums) {
    __shared__ __align__(16) ushort As[64 * 136];   // A tile (row pad +8)
    __shared__ __align__(8) ushort CsT[128 * 74];   // C tile, column-major pad 74
    __shared__ float s[128];                        // BN0 scale|shift
    __shared__ int svid[2][64];                     // voxel id per row (dbuf)

    int lane = threadIdx.x & 63, wid = threadIdx.x >> 6;
    int m = lane & 15, q = lane >> 4;   // C: col=ct*16+m, row=q*4+reg

    if (threadIdx.x < 64) {                          // BN0 finalize (folded bnfin)
        int c = threadIdx.x;
        float mu = stats[c] * (1.0f / NPTS);
        float var = stats[64 + c] * (1.0f / NPTS) - mu * mu;
        float sc = (1.0f / sqrtf(var + 1e-3f)) * g0[c];
        s[c] = sc;
        s[64 + c] = fmaf(-mu, sc, b0[c]);
    }

    // B fragments: W1T rows ct*16+m, k-chunks ks*32 + q*8 (L1/L2-hot, 32 KB)
    short8 breg[8][4];
    #pragma unroll
    for (int ct = 0; ct < 8; ++ct) {
        const ushort* br = &w1t[(ct * 16 + m) * 128 + q * 8];
        #pragma unroll
        for (int ks = 0; ks < 4; ++ks)
            breg[ct][ks] = *(const short8*)&br[ks * 32];
    }

    // contiguous point range [ps, pe) aligned to voxel boundaries
    int p0 = (int)((long long)blockIdx.x * NPTS / G2B);
    int p1 = (int)((long long)(blockIdx.x + 1) * NPTS / G2B);
    int ps, pe;
    { int v = vidx[p0]; ps = (voff[v] == (uint)p0) ? p0 : (int)voff[v + 1]; }
    if (p1 >= NPTS) pe = NPTS;
    else { int v = vidx[p1]; pe = (voff[v] == (uint)p1) ? p1 : (int)voff[v + 1]; }

    float run = -3.0e38f, csum = 0.f, csq = 0.f;
    int vcur = -1;

    // staging by 128 threads (waves 0-1)
    auto stage = [&](int r0s, int p) {
        int nrows = min(64, pe - r0s);
        for (int i = threadIdx.x; i < 512; i += 128) {   // left: bnrelu0(x0)
            int r = i >> 3, ch = i & 7, cb = ch * 8;
            uint4 o4 = make_uint4(0u, 0u, 0u, 0u);
            if (r < nrows) {
                uint4 u = *(const uint4*)(x0u + (size_t)(r0s + r) * 32 + ch * 4);
                uint w[4] = {u.x, u.y, u.z, u.w}, o[4];
                #pragma unroll
                for (int q2 = 0; q2 < 4; ++q2) {
                    float a = fmaxf(fmaf(lo16(w[q2]), s[cb + 2 * q2], s[64 + cb + 2 * q2]), 0.f);
                    float b = fmaxf(fmaf(hi16(w[q2]), s[cb + 2 * q2 + 1], s[64 + cb + 2 * q2 + 1]), 0.f);
                    o[q2] = packbf(a, b);
                }
                o4 = make_uint4(o[0], o[1], o[2], o[3]);
            }
            *(uint4*)&As[r * 136 + ch * 8] = o4;
        }
        for (int i = threadIdx.x; i < 512; i += 128) {   // right: v0 gather (post-BN0)
            int r = i >> 3, ch = i & 7;
            uint4 u = make_uint4(0u, 0u, 0u, 0u);
            if (r < nrows) u = *(const uint4*)(v0u + (size_t)vidx[r0s + r] * 32 + ch * 4);
            *(uint4*)&As[r * 136 + 64 + ch * 8] = u;
        }
        if (threadIdx.x < 64)
            svid[p][threadIdx.x] = (threadIdx.x < nrows) ? vidx[r0s + threadIdx.x] : -1;
    };

    __syncthreads();  // s ready
    if (threadIdx.x < 128 && ps < pe) stage(ps, 0);
    __syncthreads();  // As/svid[0] ready

    int sp = 0;
    for (int r0 = ps; r0 < pe; r0 += 64, sp ^= 1) {
        // MFMA phase: all waves
        const ushort* ar = &As[(wid * 16 + m) * 136 + q * 8];
        short8 a0 = *(const short8*)&ar[0];
        short8 a1 = *(const short8*)&ar[32];
        short8 a2 = *(const short8*)&ar[64];
        short8 a3 = *(const short8*)&ar[96];
        #pragma unroll
        for (int ct = 0; ct < 8; ++ct) {
            floatx4 acc = {0.f, 0.f, 0.f, 0.f};
            acc = __builtin_amdgcn_mfma_f32_16x16x32_bf16(a0, breg[ct][0], acc, 0, 0, 0);
            acc = __builtin_amdgcn_mfma_f32_16x16x32_bf16(a1, breg[ct][1], acc, 0, 0, 0);
            acc = __builtin_amdgcn_mfma_f32_16x16x32_bf16(a2, breg[ct][2], acc, 0, 0, 0);
            acc = __builtin_amdgcn_mfma_f32_16x16x32_bf16(a3, breg[ct][3], acc, 0, 0, 0);
            // column-major store: rows q*4..q*4+3 of column ct*16+m (2x b32)
            uint* cp = (uint*)&CsT[(ct * 16 + m) * 74 + wid * 16 + q * 4];
            cp[0] = packbf(acc[0], acc[1]);
            cp[1] = packbf(acc[2], acc[3]);
        }
        __syncthreads();  // CsT ready; As frag reads done

        if (threadIdx.x < 128) {
            if (r0 + 64 < pe) stage(r0 + 64, sp ^ 1);   // overwrite As for next strip
        } else {
            int c = threadIdx.x - 128;                   // segmented max over CsT col c
            const uint* crow = (const uint*)&CsT[c * 74];
            #pragma unroll 4
            for (int rp = 0; rp < 32; ++rp) {
                uint u = crow[rp];                       // rows 2rp, 2rp+1
                int va = svid[sp][2 * rp], vb = svid[sp][2 * rp + 1];
                float xa = lo16(u), xb = hi16(u);
                bool brk = (va != vcur);
                if (brk && vcur >= 0) vmaxc[(size_t)vcur * 128 + c] = bf16bits(run);
                run = brk ? xa : fmaxf(run, xa);
                vcur = va;
                csum += xa; csq = fmaf(xa, xa, csq);
                brk = (vb != vcur);
                if (brk && vcur >= 0) vmaxc[(size_t)vcur * 128 + c] = bf16bits(run);
                run = brk ? xb : fmaxf(run, xb);
                vcur = vb;
                csum += xb; csq = fmaf(xb, xb, csq);
            }
        }
        __syncthreads();  // next As/svid ready; CsT free
    }

    if (threadIdx.x >= 128) {
        int c = threadIdx.x - 128;
        if (vcur >= 0) vmaxc[(size_t)vcur * 128 + c] = bf16bits(run);
        atomicAdd(&sums[c], csum);
        atomicAdd(&sums[128 + c], csq);
    }
}

// ---------------- BN1 finalize + ReLU over voxel maxes -> dense fp32 output -----
__global__ __launch_bounds__(256) void k_bnout(const ushort* __restrict__ vmaxc,
        const uint* __restrict__ voff, const float* __restrict__ stats,
        const float* __restrict__ g1, const float* __restrict__ b1,
        float4* __restrict__ out) {
    __shared__ float s[256];
    if (threadIdx.x < 128) {
        int c = threadIdx.x;
        float mu = stats[128 + c] * (1.0f / NPTS);
        float var = stats[256 + c] * (1.0f / NPTS) - mu * mu;
        float sc = (1.0f / sqrtf(var + 1e-3f)) * g1[c];
        s[c] = sc;
        s[128 + c] = fmaf(-mu, sc, b1[c]);
    }
    __syncthreads();
    int t = blockIdx.x * 256 + threadIdx.x;
    int v = t >> 5;
    if (v >= CANVAS) return;
    int c = (t & 31) << 2;
    float4 m = make_float4(0.f, 0.f, 0.f, 0.f);
    if (voff[v + 1] != voff[v]) {      // nonempty: read max, apply monotone BN+ReLU
        uint2 u = *(const uint2*)(vmaxc + (size_t)v * 128 + c);
        m.x = fmaxf(fmaf(lo16(u.x), s[c + 0], s[128 + c + 0]), 0.f);
        m.y = fmaxf(fmaf(hi16(u.x), s[c + 1], s[128 + c + 1]), 0.f);
        m.z = fmaxf(fmaf(lo16(u.y), s[c + 2], s[128 + c + 2]), 0.f);
        m.w = fmaxf(fmaf(hi16(u.y), s[c + 3], s[128 + c + 3]), 0.f);
    }
    out[(size_t)v * 32 + (c >> 2)] = m;
}

extern "C" void kernel_launch(void* const* d_in, const int* in_sizes, int n_in,
                              void* d_out, int out_size, void* d_ws, size_t ws_size,
                              hipStream_t stream) {
    const float4* feat  = (const float4*)d_in[0];
    const int4*   coors = (const int4*)d_in[1];
    const float*  W0    = (const float*)d_in[2];
    const float*  g0    = (const float*)d_in[3];
    const float*  b0    = (const float*)d_in[4];
    const float*  W1    = (const float*)d_in[5];
    const float*  g1    = (const float*)d_in[6];
    const float*  b1    = (const float*)d_in[7];

    char* ws = (char*)d_ws;
    // workspace layout (bytes)
    int*    idxbuf = (int*)(ws + 0);               //   1,600,000
    int*    pidx   = (int*)(ws + 1600000);         //   1,600,000
    uint*   ucnt   = (uint*)(ws + 3200000);        //   1,126,400 ┐ one memset
    float*  stats  = (float*)(ws + 4326400);       //       3,072 ┘ (768 floats)
    //   [0:64] sum0, [64:128] sq0, [128:256] sum1, [256:384] sq1
    uint*   voff   = (uint*)(ws + 4329472);        //   1,126,416 (CANVAS+1)
    uint*   bsum   = (uint*)(ws + 5455888);        //       4,096
    int*    vidx   = (int*)(ws + 5459984);         //   1,600,000
    float*  featS  = (float*)(ws + 7059984);       //   6,400,000 (sorted float4)
    float*  vmean  = (float*)(ws + 13459984);      //   4,505,600
    ushort* w1t    = (ushort*)(ws + 17965584);     //      32,768
    uint*   x0u    = (uint*)(ws + 17998352);       //  51,200,000 (pre-BN bf16, sorted)
    uint*   v0u    = (uint*)(ws + 69198352);       //  36,044,800 (post-BN0-ReLU max, bf16)
    ushort* vmaxc  = (ushort*)(ws + 105243152);    //  72,089,600 (pre-BN1 voxel max, bf16)
    // total: 177,332,752 bytes

    hipMemsetAsync(ws + 3200000, 0, 1129472, stream);  // ucnt + stats in one shot

    const int BLK = 256;
    int gpts = (NPTS + BLK - 1) / BLK;    // 1563
    int gvox = (CANVAS + BLK - 1) / BLK;  // 1100

    k_bucket<<<gpts + 64, BLK, 0, stream>>>(coors, W1, idxbuf, pidx, ucnt, w1t);
    k_scanA<<<SCANB, 1024, 0, stream>>>(ucnt, voff, bsum);
    k_scanC<<<SCANB, 1024, 0, stream>>>(bsum, voff);
    k_perm<<<gpts, BLK, 0, stream>>>(idxbuf, pidx, voff, feat, vidx, (float4*)featS);
    k_vmean<<<gvox, BLK, 0, stream>>>((const float4*)featS, voff, (float4*)vmean);
    k_gemm1<<<gpts, BLK, 0, stream>>>((const float4*)featS, vidx, (const float4*)vmean,
                                      W0, x0u, stats);
    k_vmax0<<<CANVAS * 16 / BLK, BLK, 0, stream>>>(x0u, voff, stats, g0, b0, v0u);
    k_gemm2p<<<G2B, BLK, 0, stream>>>(x0u, v0u, vidx, voff, stats, g0, b0, w1t,
                                      vmaxc, stats + 128);
    k_bnout<<<CANVAS * 32 / BLK, BLK, 0, stream>>>(vmaxc, voff, stats, g1, b1,
                                                   (float4*)d_out);
}